// Round 1
// baseline (119.537 us; speedup 1.0000x reference)
//
#include <hip/hip_runtime.h>
#include <math.h>

// Problem constants (fixed by the reference): Q=4, N=64, H=256, C=1, L=1024
#define QQ 4
#define NN 64
#define HH 256
#define LL 1024
#define LH 513   // L/2 + 1 rfft bins actually consumed by irfft(n=1024)

// One block per (q,h). Phase A: compute X[l] = unit_l * kernel_l for l=0..512
// into LDS. Phase B: length-1024 inverse real DFT from the 513 bins, each
// thread produces 4 output samples via an angle-recurrence (exact refresh
// every 64 steps with sinpif/cospif).
//
// Math notes (derived from the reference):
//   omega^l = exp(-2*pi*i*l/L)
//   z_l  = 2(1-w)/(1+w) = 2i*tan(pi*l/L)          (purely imaginary)
//   unit = 2/(1+w)      = 1 + i*tan(pi*l/L)
//   zt   = z_l / t ;  r_n = 1/(zt - d_n) = 1/(a_n + i*zeta),
//          a_n = exp(diagonal) , zeta = 2*tan(pi*l/L)/t
//   k_ij = sum_n w_ij[n] * r_n  with real weights
//          w00=B*C, w01=B*P, w10=P*C, w11=P*P
//   kernel = k00 - k10*k01/(1+k11) ;  X_l = unit * kernel
//   l=512 limit: X = (t/2) * sum_n B_n*C_n  (real)
//   irfft: out[s] = (1/L)*( Re X_0 + (-1)^s Re X_512
//                         + 2*sum_{l=1}^{511} (Xr_l cos(2pi l s/L) - Xi_l sin(2pi l s/L)) )

__global__ __launch_bounds__(256)
void tssm_kernel(const float* __restrict__ diagonal,      // [Q][N]
                 const float* __restrict__ lowrank,       // [Q][N]
                 const float* __restrict__ timestep,      // [Q][H]
                 const float* __restrict__ input_matrix,  // [Q][N]
                 const float* __restrict__ output_matrix, // [Q][1][H][N]
                 float* __restrict__ out)                 // [L][Q][1][H]
{
    __shared__ float sh_a[NN], sh_a2[NN];
    __shared__ float sh_w00[NN], sh_w01[NN], sh_w10[NN], sh_w11[NN];
    __shared__ float sXr[LH], sXi[LH];

    const int b   = blockIdx.x;      // 0..Q*H-1
    const int q   = b >> 8;          // / H
    const int h   = b & (HH - 1);
    const int tid = threadIdx.x;

    if (tid < NN) {
        float a  = expf(diagonal[q * NN + tid]);             // a = -d > 0
        float B  = input_matrix[q * NN + tid];
        float P  = lowrank[q * NN + tid];
        float Cm = output_matrix[(q * HH + h) * NN + tid];   // c = 0 (C==1)
        sh_a[tid]   = a;
        sh_a2[tid]  = a * a;
        sh_w00[tid] = B * Cm;
        sh_w01[tid] = B * P;
        sh_w10[tid] = P * Cm;
        sh_w11[tid] = P * P;
    }
    __syncthreads();

    const float t    = expf(timestep[q * HH + h]);
    const float invt = __builtin_amdgcn_rcpf(t);

    // ---------------- Phase A: spectrum X[0..512] ----------------
    for (int l = tid; l < LH; l += 256) {
        float Xr, Xi;
        if (l == 512) {
            float s00 = 0.0f;
            for (int n = 0; n < NN; ++n) s00 += sh_w00[n];
            Xr = 0.5f * t * s00;
            Xi = 0.0f;
        } else {
            float f    = (float)l * (1.0f / 1024.0f);
            float sp   = sinpif(f);
            float cp   = cospif(f);
            float tn   = sp * __builtin_amdgcn_rcpf(cp);     // tan(pi*l/1024), >= 0
            float zeta = 2.0f * tn * invt;
            float z2   = zeta * zeta;

            float k00r = 0.f, k00i = 0.f, k01r = 0.f, k01i = 0.f;
            float k10r = 0.f, k10i = 0.f, k11r = 0.f, k11i = 0.f;
            #pragma unroll 8
            for (int n = 0; n < NN; ++n) {
                float inv = __builtin_amdgcn_rcpf(sh_a2[n] + z2);
                float rr  = sh_a[n] * inv;       // Re r_n
                float ri  = -zeta * inv;         // Im r_n
                k00r = fmaf(sh_w00[n], rr, k00r); k00i = fmaf(sh_w00[n], ri, k00i);
                k01r = fmaf(sh_w01[n], rr, k01r); k01i = fmaf(sh_w01[n], ri, k01i);
                k10r = fmaf(sh_w10[n], rr, k10r); k10i = fmaf(sh_w10[n], ri, k10i);
                k11r = fmaf(sh_w11[n], rr, k11r); k11i = fmaf(sh_w11[n], ri, k11i);
            }
            // kernel = k00 - (k10*k01)/(1+k11)
            float dr   = 1.0f + k11r, di = k11i;         // dr > 1, no singularity
            float nr   = k10r * k01r - k10i * k01i;
            float ni   = k10r * k01i + k10i * k01r;
            float invm = __builtin_amdgcn_rcpf(fmaf(dr, dr, di * di));
            float qr   = (nr * dr + ni * di) * invm;
            float qi   = (ni * dr - nr * di) * invm;
            float kr   = k00r - qr, ki = k00i - qi;
            // X = (1 + i*tn) * kernel
            Xr = fmaf(-tn, ki, kr);
            Xi = fmaf( tn, kr, ki);
        }
        sXr[l] = Xr;
        sXi[l] = Xi;
    }
    __syncthreads();

    // ---------------- Phase B: inverse real DFT ----------------
    const float X0   = sXr[0];
    const float X512 = sXr[512];

    float acc[4], cc[4], sn[4], dc[4], dsn[4];
    int   sv[4];
    #pragma unroll
    for (int k = 0; k < 4; ++k) {
        sv[k]  = tid + (k << 8);
        acc[k] = 0.0f;
        float fd = (float)sv[k] * (1.0f / 512.0f);  // 2*pi*s/1024 in pi units
        dc[k]  = cospif(fd);
        dsn[k] = sinpif(fd);
        cc[k]  = 1.0f;   // angle 0 (l=0 state; advanced before first use)
        sn[k]  = 0.0f;
    }

    for (int l = 1; l < 512; ++l) {
        if ((l & 63) == 1) {
            // exact refresh: angle = 2*pi*(s*l mod 1024)/1024
            #pragma unroll
            for (int k = 0; k < 4; ++k) {
                int   m  = (sv[k] * l) & 1023;
                float fm = (float)m * (1.0f / 512.0f);
                cc[k] = cospif(fm);
                sn[k] = sinpif(fm);
            }
        } else {
            #pragma unroll
            for (int k = 0; k < 4; ++k) {
                float c2 = fmaf(cc[k], dc[k], -sn[k] * dsn[k]);
                sn[k]    = fmaf(sn[k], dc[k],  cc[k] * dsn[k]);
                cc[k]    = c2;
            }
        }
        float xr = sXr[l], xi = sXi[l];
        #pragma unroll
        for (int k = 0; k < 4; ++k) {
            acc[k] = fmaf(xr, cc[k], acc[k]);
            acc[k] = fmaf(-xi, sn[k], acc[k]);
        }
    }

    const float invL = 1.0f / 1024.0f;
    #pragma unroll
    for (int k = 0; k < 4; ++k) {
        int   s   = sv[k];
        float sgn = (s & 1) ? -1.0f : 1.0f;
        float val = (X0 + sgn * X512 + 2.0f * acc[k]) * invL;
        out[(s * QQ + q) * HH + h] = val;   // [L][Q][1][H]
    }
}

extern "C" void kernel_launch(void* const* d_in, const int* in_sizes, int n_in,
                              void* d_out, int out_size, void* d_ws, size_t ws_size,
                              hipStream_t stream) {
    (void)in_sizes; (void)n_in; (void)out_size; (void)d_ws; (void)ws_size;
    const float* diagonal      = (const float*)d_in[0];
    const float* lowrank       = (const float*)d_in[1];
    const float* timestep      = (const float*)d_in[2];
    const float* input_matrix  = (const float*)d_in[3];
    const float* output_matrix = (const float*)d_in[4];
    float* out = (float*)d_out;

    dim3 grid(QQ * HH);
    dim3 block(256);
    hipLaunchKernelGGL(tssm_kernel, grid, block, 0, stream,
                       diagonal, lowrank, timestep, input_matrix, output_matrix, out);
}

// Round 2
// 39.755 us; speedup vs baseline: 3.0068x; 3.0068x over previous
//
#include <hip/hip_runtime.h>
#include <math.h>

// Problem constants: Q=4, N=64, H=256, C=1, L=1024
#define QQ 4
#define NN 64
#define HH 256

// Phase A: X[l] = (1 + i*tan(pi*l/1024)) * (k00 - k10*k01/(1+k11)), l=0..511
//          X[512] = (t/2) * sum_n B*C (real limit)
// Phase B: irfft via parity-split accumulators + quadruple output symmetry:
//   thread s in [0,255], CE/CO/SE/SO = sums of Xr*cos / Xi*sin over even/odd l.
//   out[s]      = (X0 + (-1)^s X512 + 2(CE+CO-SE-SO))/1024
//   out[1024-s] = ... 2(CE+CO+SE+SO) ...      (s>=1)
//   out[512+s]  = ... 2(CE-CO-SE+SO) ...
//   out[512-s]  = ... 2(CE-CO+SE-SO) ...
//   s=256/768 (self-paired quadruple) via wave-0 alternating-sign reduction.

__global__ __launch_bounds__(256)
void tssm_kernel(const float* __restrict__ diagonal,      // [Q][N]
                 const float* __restrict__ lowrank,       // [Q][N]
                 const float* __restrict__ timestep,      // [Q][H]
                 const float* __restrict__ input_matrix,  // [Q][N]
                 const float* __restrict__ output_matrix, // [Q][1][H][N]
                 float* __restrict__ out)                 // [L][Q][1][H]
{
    __shared__ float4 sP4[NN];     // (a, a^2, w00=B*C, w01=B*P)
    __shared__ float2 sP2[NN];     // (w10=P*C, w11=P*P)
    __shared__ float4 sXp[256];    // bin pairs: (Xr[2k], Xi[2k], Xr[2k+1], Xi[2k+1])
    __shared__ float  sX512;

    const int b   = blockIdx.x;    // 0..Q*H-1
    const int q   = b >> 8;
    const int h   = b & (HH - 1);
    const int tid = threadIdx.x;

    if (tid < NN) {
        float a  = expf(diagonal[q * NN + tid]);
        float B  = input_matrix[q * NN + tid];
        float P  = lowrank[q * NN + tid];
        float Cm = output_matrix[(q * HH + h) * NN + tid];
        sP4[tid] = make_float4(a, a * a, B * Cm, B * P);
        sP2[tid] = make_float2(P * Cm, P * P);
    }
    __syncthreads();

    const float t    = expf(timestep[q * HH + h]);
    const float invt = __builtin_amdgcn_rcpf(t);

    // ---------------- Phase A: two bins per thread ----------------
    {
        const int l1 = tid;          // 0..255
        const int l2 = tid + 256;    // 256..511
        float tn[2], ze[2], z2[2];
        {
            float f1 = (float)l1 * (1.0f / 1024.0f);
            float f2 = (float)l2 * (1.0f / 1024.0f);
            tn[0] = sinpif(f1) * __builtin_amdgcn_rcpf(cospif(f1));
            tn[1] = sinpif(f2) * __builtin_amdgcn_rcpf(cospif(f2));
            ze[0] = 2.0f * tn[0] * invt;  ze[1] = 2.0f * tn[1] * invt;
            z2[0] = ze[0] * ze[0];        z2[1] = ze[1] * ze[1];
        }
        float kr[2][4] = {{0,0,0,0},{0,0,0,0}};
        float ki[2][4] = {{0,0,0,0},{0,0,0,0}};
        float s00 = 0.0f;
        #pragma unroll 4
        for (int n = 0; n < NN; ++n) {
            float4 p4 = sP4[n];
            float2 p2 = sP2[n];
            s00 += p4.z;
            float w0 = p4.z, w1 = p4.w, w2 = p2.x, w3 = p2.y;
            #pragma unroll
            for (int bb = 0; bb < 2; ++bb) {
                float inv = __builtin_amdgcn_rcpf(p4.y + z2[bb]);
                float rr  = p4.x * inv;
                float ri  = -ze[bb] * inv;
                kr[bb][0] = fmaf(w0, rr, kr[bb][0]); ki[bb][0] = fmaf(w0, ri, ki[bb][0]);
                kr[bb][1] = fmaf(w1, rr, kr[bb][1]); ki[bb][1] = fmaf(w1, ri, ki[bb][1]);
                kr[bb][2] = fmaf(w2, rr, kr[bb][2]); ki[bb][2] = fmaf(w2, ri, ki[bb][2]);
                kr[bb][3] = fmaf(w3, rr, kr[bb][3]); ki[bb][3] = fmaf(w3, ri, ki[bb][3]);
            }
        }
        #pragma unroll
        for (int bb = 0; bb < 2; ++bb) {
            float dr   = 1.0f + kr[bb][3], di = ki[bb][3];
            float nr   = kr[bb][2] * kr[bb][1] - ki[bb][2] * ki[bb][1];
            float ni   = kr[bb][2] * ki[bb][1] + ki[bb][2] * kr[bb][1];
            float invm = __builtin_amdgcn_rcpf(fmaf(dr, dr, di * di));
            float qr   = (nr * dr + ni * di) * invm;
            float qi   = (ni * dr - nr * di) * invm;
            float Kr   = kr[bb][0] - qr, Ki = ki[bb][0] - qi;
            float Xr   = fmaf(-tn[bb], Ki, Kr);
            float Xi   = fmaf( tn[bb], Kr, Ki);
            ((float2*)sXp)[bb ? l2 : l1] = make_float2(Xr, Xi);
        }
        if (tid == 0) sX512 = 0.5f * t * s00;
    }
    __syncthreads();

    // ---------------- Phase B ----------------
    const float X0    = sXp[0].x;
    const float X512v = sX512;
    const int   s     = tid;
    const float i512  = 1.0f / 512.0f;

    float CE = 0.f, CO = 0.f, SE = 0.f, SO = 0.f;
    const float c1  = cospif((float)s * i512);
    const float s1  = sinpif((float)s * i512);
    const float twc = 2.0f * c1;
    {
        float2 x1 = ((const float2*)sXp)[1];   // bin l=1 (odd)
        CO = x1.x * c1;
        SO = x1.y * s1;
    }

    // bins 2..511 as 255 pairs, 17 segments of 15 pairs, Chebyshev refresh per seg
    for (int seg = 0; seg < 17; ++seg) {
        const int le0 = 2 + seg * 30;              // even
        int   m1 = (s * (le0 - 1)) & 1023;
        int   m2 = (s * le0) & 1023;
        float cA = cospif((float)m1 * i512);
        float sA = sinpif((float)m1 * i512);
        float cB = cospif((float)m2 * i512);
        float sB = sinpif((float)m2 * i512);
        const int p0 = le0 >> 1;
        #pragma unroll
        for (int k = 0; k < 15; ++k) {
            float4 xp = sXp[p0 + k];
            // even bin le0+2k : state (cB,sB)
            CE = fmaf(xp.x, cB, CE);
            SE = fmaf(xp.y, sB, SE);
            // odd bin le0+2k+1
            float cC = fmaf(twc, cB, -cA);
            float sC = fmaf(twc, sB, -sA);
            CO = fmaf(xp.z, cC, CO);
            SO = fmaf(xp.w, sC, SO);
            // advance to next even
            float cN = fmaf(twc, cC, -cB);
            float sN = fmaf(twc, sC, -sB);
            cA = cC; cB = cN;
            sA = sC; sB = sN;
        }
    }

    const float invL = 1.0f / 1024.0f;
    const float sgn  = (s & 1) ? -1.0f : 1.0f;
    const float base = fmaf(sgn, X512v, X0);
    const float SC = CE + CO, SS = SE + SO, DC = CE - CO, DS = SE - SO;

    out[((s * QQ + q) << 8) + h] = (base + 2.0f * (SC - SS)) * invL;
    if (s > 0)
        out[(((1024 - s) * QQ + q) << 8) + h] = (base + 2.0f * (SC + SS)) * invL;
    out[(((512 + s) * QQ + q) << 8) + h] = (base + 2.0f * (DC - DS)) * invL;
    out[(((512 - s) * QQ + q) << 8) + h] = (base + 2.0f * (DC + DS)) * invL;

    // ---- s = 256 / 768 (missing quadruple): wave 0 reduction ----
    // out[256] needs SumC = sum_{even l>=2} Xr_l*(-1)^(l/2), SumS = sum_{odd l} Xi_l*(-1)^((l-1)/2)
    // pair p holds even bin 2p (Xr=.x) and odd bin 2p+1 (Xi=.w); both signs = (-1)^p.
    if (tid < 64) {
        const float sgnp = (tid & 1) ? -1.0f : 1.0f;
        float accC = 0.f, accS = 0.f;
        #pragma unroll
        for (int m = 0; m < 4; ++m) {
            int    p  = tid + (m << 6);
            float4 xp = sXp[p];
            float  xr = (p == 0) ? 0.0f : xp.x;   // exclude l=0
            accC = fmaf(sgnp, xr,   accC);
            accS = fmaf(sgnp, xp.w, accS);
        }
        #pragma unroll
        for (int off = 32; off >= 1; off >>= 1) {
            accC += __shfl_xor(accC, off, 64);
            accS += __shfl_xor(accS, off, 64);
        }
        if (tid == 0) {
            float b2 = X0 + X512v;
            out[((256 * QQ + q) << 8) + h] = (b2 + 2.0f * (accC - accS)) * invL;
            out[((768 * QQ + q) << 8) + h] = (b2 + 2.0f * (accC + accS)) * invL;
        }
    }
}

extern "C" void kernel_launch(void* const* d_in, const int* in_sizes, int n_in,
                              void* d_out, int out_size, void* d_ws, size_t ws_size,
                              hipStream_t stream) {
    (void)in_sizes; (void)n_in; (void)out_size; (void)d_ws; (void)ws_size;
    const float* diagonal      = (const float*)d_in[0];
    const float* lowrank       = (const float*)d_in[1];
    const float* timestep      = (const float*)d_in[2];
    const float* input_matrix  = (const float*)d_in[3];
    const float* output_matrix = (const float*)d_in[4];
    float* out = (float*)d_out;

    hipLaunchKernelGGL(tssm_kernel, dim3(QQ * HH), dim3(256), 0, stream,
                       diagonal, lowrank, timestep, input_matrix, output_matrix, out);
}

// Round 3
// 27.867 us; speedup vs baseline: 4.2895x; 1.4266x over previous
//
#include <hip/hip_runtime.h>
#include <math.h>

// Problem constants: Q=4, N=64, H=256, C=1, L=1024
#define QQ 4
#define NN 64
#define HH 256

// One block per (q,h), 256 threads.
//
// Phase A (per thread: bins l=t and l=t+256):
//   z_l = 2i*tan(pi*l/1024); unit_l = 1 + i*tan(pi*l/1024)
//   r_n = 1/(a_n + i*zeta), a = exp(diag), zeta = 2*tan(pi*l/1024)/t
//   k_ij = sum_n w_ij * r_n,  w00=B*C, w01=B*P, w10=P*C, w11=P*P
//   X_l = unit_l * (k00 - k10*k01/(1+k11));  X_512 = (t/2)*sum_n B*C (real)
//   Pole data read via block-uniform addresses -> scalar loads (no LDS).
//
// Phase B: irfft(1024) via one 512-pt complex inverse FFT (Stockham radix-2):
//   E'[k] = (X[k] + conj(X[512-k]))/2
//   O'[k] = e^{+2pi i k/1024} * (X[k] - conj(X[512-k]))/2
//   Y[k]  = E'[k] + i*O'[k]
//   y = unscaled inverse DFT_512(Y); x[2m] = Re y[m]/512, x[2m+1] = Im y[m]/512
//   Stage Ns=1 fused in registers (thread t holds Y[t], Y[t+256]);
//   stage Ns=256 streams results straight to global.
//   Stockham step (inverse, sign +):
//     u = src[j]; v = src[j+256] * e^{+i*pi*(j mod Ns)/Ns}
//     dj = (j div Ns)*2Ns + (j mod Ns); dst[dj] = u+v; dst[dj+Ns] = u-v

__global__ __launch_bounds__(256)
void tssm_kernel(const float* __restrict__ diagonal,      // [Q][N]
                 const float* __restrict__ lowrank,       // [Q][N]
                 const float* __restrict__ timestep,      // [Q][H]
                 const float* __restrict__ input_matrix,  // [Q][N]
                 const float* __restrict__ output_matrix, // [Q][1][H][N]
                 float* __restrict__ out)                 // [L][Q][1][H]
{
    __shared__ __align__(16) float2 bufA[512];
    __shared__ __align__(16) float2 bufB[513];   // phase A spectrum X lives here too

    const int b = blockIdx.x;
    const int q = b >> 8;
    const int h = b & (HH - 1);
    const int t = threadIdx.x;

    const float tv   = expf(timestep[q * HH + h]);
    const float invt = __builtin_amdgcn_rcpf(tv);

    const float* dgq = diagonal      + q * NN;
    const float* Bq  = input_matrix  + q * NN;
    const float* Pq  = lowrank       + q * NN;
    const float* Cq  = output_matrix + (q * HH + h) * NN;

    // ---------------- Phase A ----------------
    const float f1  = (float)t         * (1.0f / 1024.0f);
    const float f2  = (float)(t + 256) * (1.0f / 1024.0f);
    const float tn0 = sinpif(f1) * __builtin_amdgcn_rcpf(cospif(f1));
    const float tn1 = sinpif(f2) * __builtin_amdgcn_rcpf(cospif(f2));
    const float ze0 = 2.0f * tn0 * invt, ze1 = 2.0f * tn1 * invt;
    const float z20 = ze0 * ze0,         z21 = ze1 * ze1;

    float k0r0=0,k0r1=0,k0r2=0,k0r3=0, k0i0=0,k0i1=0,k0i2=0,k0i3=0;
    float k1r0=0,k1r1=0,k1r2=0,k1r3=0, k1i0=0,k1i1=0,k1i2=0,k1i3=0;
    float s00 = 0.0f;

    #pragma unroll 8
    for (int n = 0; n < NN; ++n) {
        float dg = dgq[n], B = Bq[n], P = Pq[n], Cm = Cq[n];  // uniform -> s_load
        float a  = __expf(dg);
        float a2 = a * a;
        float w0 = B * Cm, w1 = B * P, w2 = P * Cm, w3 = P * P;
        s00 += w0;
        {
            float inv = __builtin_amdgcn_rcpf(a2 + z20);
            float rr = a * inv, ri = -ze0 * inv;
            k0r0 = fmaf(w0, rr, k0r0); k0i0 = fmaf(w0, ri, k0i0);
            k0r1 = fmaf(w1, rr, k0r1); k0i1 = fmaf(w1, ri, k0i1);
            k0r2 = fmaf(w2, rr, k0r2); k0i2 = fmaf(w2, ri, k0i2);
            k0r3 = fmaf(w3, rr, k0r3); k0i3 = fmaf(w3, ri, k0i3);
        }
        {
            float inv = __builtin_amdgcn_rcpf(a2 + z21);
            float rr = a * inv, ri = -ze1 * inv;
            k1r0 = fmaf(w0, rr, k1r0); k1i0 = fmaf(w0, ri, k1i0);
            k1r1 = fmaf(w1, rr, k1r1); k1i1 = fmaf(w1, ri, k1i1);
            k1r2 = fmaf(w2, rr, k1r2); k1i2 = fmaf(w2, ri, k1i2);
            k1r3 = fmaf(w3, rr, k1r3); k1i3 = fmaf(w3, ri, k1i3);
        }
    }

    {   // bin l1 = t
        float dr = 1.0f + k0r3, di = k0i3;
        float nr = k0r2 * k0r1 - k0i2 * k0i1;
        float ni = k0r2 * k0i1 + k0i2 * k0r1;
        float invm = __builtin_amdgcn_rcpf(fmaf(dr, dr, di * di));
        float qr = (nr * dr + ni * di) * invm;
        float qi = (ni * dr - nr * di) * invm;
        float Kr = k0r0 - qr, Ki = k0i0 - qi;
        bufB[t] = make_float2(fmaf(-tn0, Ki, Kr), fmaf(tn0, Kr, Ki));
    }
    {   // bin l2 = t + 256
        float dr = 1.0f + k1r3, di = k1i3;
        float nr = k1r2 * k1r1 - k1i2 * k1i1;
        float ni = k1r2 * k1i1 + k1i2 * k1r1;
        float invm = __builtin_amdgcn_rcpf(fmaf(dr, dr, di * di));
        float qr = (nr * dr + ni * di) * invm;
        float qi = (ni * dr - nr * di) * invm;
        float Kr = k1r0 - qr, Ki = k1i0 - qi;
        bufB[t + 256] = make_float2(fmaf(-tn1, Ki, Kr), fmaf(tn1, Kr, Ki));
    }
    if (t == 0) bufB[512] = make_float2(0.5f * tv * s00, 0.0f);
    __syncthreads();

    // ---------------- Y build (k = t and k = t+256) ----------------
    const float c1 = cospif((float)t * (1.0f / 512.0f));
    const float s1 = sinpif((float)t * (1.0f / 512.0f));

    float Y0r, Y0i, Y1r, Y1i;
    {   // k = t : A = X[t], Bc = conj(X[512-t]), tw = (c1, s1)
        float2 A = bufB[t], Bv = bufB[512 - t];
        float Dr = A.x - Bv.x, Di = A.y + Bv.y;
        float twDr = fmaf(c1, Dr, -s1 * Di);
        float twDi = fmaf(c1, Di,  s1 * Dr);
        Y0r = 0.5f * (A.x + Bv.x) - 0.5f * twDi;
        Y0i = 0.5f * (A.y - Bv.y) + 0.5f * twDr;
    }
    {   // k = t+256 : A = X[t+256], Bc = conj(X[256-t]), tw = (-s1, c1)
        float2 A = bufB[t + 256], Bv = bufB[256 - t];
        float Dr = A.x - Bv.x, Di = A.y + Bv.y;
        float twDr = fmaf(-s1, Dr, -c1 * Di);
        float twDi = fmaf(-s1, Di,  c1 * Dr);
        Y1r = 0.5f * (A.x + Bv.x) - 0.5f * twDi;
        Y1i = 0.5f * (A.y - Bv.y) + 0.5f * twDr;
    }

    // ---------------- Stage Ns=1 (in registers), write bufA ----------------
    {
        float4 st0 = make_float4(Y0r + Y1r, Y0i + Y1i, Y0r - Y1r, Y0i - Y1i);
        ((float4*)bufA)[t] = st0;   // bufA[2t], bufA[2t+1]
    }
    __syncthreads();

    // ---------------- Stages Ns = 2..128 (LDS ping-pong) ----------------
    #define FFT_STAGE(NS, INVNS, SRC, DST)                                   \
    {                                                                        \
        float2 u = (SRC)[t];                                                 \
        float2 v = (SRC)[t + 256];                                           \
        int   base = t & ((NS) - 1);                                         \
        float r  = (float)base * (INVNS);                                    \
        float cw = cospif(r), sw = sinpif(r);                                \
        float vr = fmaf(cw, v.x, -sw * v.y);                                 \
        float vi = fmaf(cw, v.y,  sw * v.x);                                 \
        int dj = ((t & ~((NS) - 1)) << 1) | base;                            \
        (DST)[dj]        = make_float2(u.x + vr, u.y + vi);                  \
        (DST)[dj + (NS)] = make_float2(u.x - vr, u.y - vi);                  \
        __syncthreads();                                                     \
    }

    FFT_STAGE(2,   0.5f,        bufA, bufB)
    FFT_STAGE(4,   0.25f,       bufB, bufA)
    FFT_STAGE(8,   0.125f,      bufA, bufB)
    FFT_STAGE(16,  0.0625f,     bufB, bufA)
    FFT_STAGE(32,  0.03125f,    bufA, bufB)
    FFT_STAGE(64,  0.015625f,   bufB, bufA)
    FFT_STAGE(128, 0.0078125f,  bufA, bufB)
    #undef FFT_STAGE

    // ---------------- Stage Ns=256 -> straight to global ----------------
    {
        float2 u = bufB[t];
        float2 v = bufB[t + 256];
        float r  = (float)t * (1.0f / 256.0f);
        float cw = cospif(r), sw = sinpif(r);
        float vr = fmaf(cw, v.x, -sw * v.y);
        float vi = fmaf(cw, v.y,  sw * v.x);
        // m1 = t: y = u + tw*v ; m2 = t+256: y = u - tw*v
        const float sc = 1.0f / 512.0f;
        const int base_out = (q << 8) + h;
        int s0 = 2 * t;          // x[s0] = Re(y_m1), x[s0+1] = Im(y_m1)
        int s2 = 2 * t + 512;    // x[s2] = Re(y_m2), x[s2+1] = Im(y_m2)
        out[base_out + (s0       << 10)] = (u.x + vr) * sc;
        out[base_out + ((s0 + 1) << 10)] = (u.y + vi) * sc;
        out[base_out + (s2       << 10)] = (u.x - vr) * sc;
        out[base_out + ((s2 + 1) << 10)] = (u.y - vi) * sc;
    }
}

extern "C" void kernel_launch(void* const* d_in, const int* in_sizes, int n_in,
                              void* d_out, int out_size, void* d_ws, size_t ws_size,
                              hipStream_t stream) {
    (void)in_sizes; (void)n_in; (void)out_size; (void)d_ws; (void)ws_size;
    const float* diagonal      = (const float*)d_in[0];
    const float* lowrank       = (const float*)d_in[1];
    const float* timestep      = (const float*)d_in[2];
    const float* input_matrix  = (const float*)d_in[3];
    const float* output_matrix = (const float*)d_in[4];
    float* out = (float*)d_out;

    hipLaunchKernelGGL(tssm_kernel, dim3(QQ * HH), dim3(256), 0, stream,
                       diagonal, lowrank, timestep, input_matrix, output_matrix, out);
}

// Round 4
// 27.088 us; speedup vs baseline: 4.4129x; 1.0288x over previous
//
#include <hip/hip_runtime.h>
#include <math.h>

// Problem constants: Q=4, N=64, H=256, C=1, L=1024
#define QQ 4
#define NN 64
#define HH 256

// Kernel 1: one block per (q,h), 256 threads.
//   Phase A: spectrum X[l] (resolvent sums, rank-1 correction), l = t, t+256.
//   Phase B: irfft(1024) via 512-pt complex inverse Stockham FFT in LDS.
//   Output x[s], s=0..1023, written COALESCED to ws[q][h][s] (float2 lanes).
// Kernel 2: 64x64 LDS tile transpose ws[q][h][s] -> out[s][q][h].

__global__ __launch_bounds__(256)
void tssm_kernel(const float* __restrict__ diagonal,      // [Q][N]
                 const float* __restrict__ lowrank,       // [Q][N]
                 const float* __restrict__ timestep,      // [Q][H]
                 const float* __restrict__ input_matrix,  // [Q][N]
                 const float* __restrict__ output_matrix, // [Q][1][H][N]
                 float* __restrict__ ws)                  // [Q][H][L] scratch
{
    __shared__ __align__(16) float2 bufA[512];
    __shared__ __align__(16) float2 bufB[513];

    const int b = blockIdx.x;
    const int q = b >> 8;
    const int h = b & (HH - 1);
    const int t = threadIdx.x;

    const float tv   = expf(timestep[q * HH + h]);
    const float invt = __builtin_amdgcn_rcpf(tv);

    const float* dgq = diagonal      + q * NN;
    const float* Bq  = input_matrix  + q * NN;
    const float* Pq  = lowrank       + q * NN;
    const float* Cq  = output_matrix + (q * HH + h) * NN;

    // ---------------- Phase A ----------------
    const float f1  = (float)t         * (1.0f / 1024.0f);
    const float f2  = (float)(t + 256) * (1.0f / 1024.0f);
    const float tn0 = sinpif(f1) * __builtin_amdgcn_rcpf(cospif(f1));
    const float tn1 = sinpif(f2) * __builtin_amdgcn_rcpf(cospif(f2));
    const float ze0 = 2.0f * tn0 * invt, ze1 = 2.0f * tn1 * invt;
    const float z20 = ze0 * ze0,         z21 = ze1 * ze1;

    float k0r0=0,k0r1=0,k0r2=0,k0r3=0, k0i0=0,k0i1=0,k0i2=0,k0i3=0;
    float k1r0=0,k1r1=0,k1r2=0,k1r3=0, k1i0=0,k1i1=0,k1i2=0,k1i3=0;
    float s00 = 0.0f;

    #pragma unroll 8
    for (int n = 0; n < NN; ++n) {
        float dg = dgq[n], B = Bq[n], P = Pq[n], Cm = Cq[n];  // uniform -> s_load
        float a  = __expf(dg);
        float a2 = a * a;
        float w0 = B * Cm, w1 = B * P, w2 = P * Cm, w3 = P * P;
        s00 += w0;
        {
            float inv = __builtin_amdgcn_rcpf(a2 + z20);
            float rr = a * inv, ri = -ze0 * inv;
            k0r0 = fmaf(w0, rr, k0r0); k0i0 = fmaf(w0, ri, k0i0);
            k0r1 = fmaf(w1, rr, k0r1); k0i1 = fmaf(w1, ri, k0i1);
            k0r2 = fmaf(w2, rr, k0r2); k0i2 = fmaf(w2, ri, k0i2);
            k0r3 = fmaf(w3, rr, k0r3); k0i3 = fmaf(w3, ri, k0i3);
        }
        {
            float inv = __builtin_amdgcn_rcpf(a2 + z21);
            float rr = a * inv, ri = -ze1 * inv;
            k1r0 = fmaf(w0, rr, k1r0); k1i0 = fmaf(w0, ri, k1i0);
            k1r1 = fmaf(w1, rr, k1r1); k1i1 = fmaf(w1, ri, k1i1);
            k1r2 = fmaf(w2, rr, k1r2); k1i2 = fmaf(w2, ri, k1i2);
            k1r3 = fmaf(w3, rr, k1r3); k1i3 = fmaf(w3, ri, k1i3);
        }
    }

    {   // bin l1 = t
        float dr = 1.0f + k0r3, di = k0i3;
        float nr = k0r2 * k0r1 - k0i2 * k0i1;
        float ni = k0r2 * k0i1 + k0i2 * k0r1;
        float invm = __builtin_amdgcn_rcpf(fmaf(dr, dr, di * di));
        float qr = (nr * dr + ni * di) * invm;
        float qi = (ni * dr - nr * di) * invm;
        float Kr = k0r0 - qr, Ki = k0i0 - qi;
        bufB[t] = make_float2(fmaf(-tn0, Ki, Kr), fmaf(tn0, Kr, Ki));
    }
    {   // bin l2 = t + 256
        float dr = 1.0f + k1r3, di = k1i3;
        float nr = k1r2 * k1r1 - k1i2 * k1i1;
        float ni = k1r2 * k1i1 + k1i2 * k1r1;
        float invm = __builtin_amdgcn_rcpf(fmaf(dr, dr, di * di));
        float qr = (nr * dr + ni * di) * invm;
        float qi = (ni * dr - nr * di) * invm;
        float Kr = k1r0 - qr, Ki = k1i0 - qi;
        bufB[t + 256] = make_float2(fmaf(-tn1, Ki, Kr), fmaf(tn1, Kr, Ki));
    }
    if (t == 0) bufB[512] = make_float2(0.5f * tv * s00, 0.0f);
    __syncthreads();

    // ---------------- Y build ----------------
    const float c1 = cospif((float)t * (1.0f / 512.0f));
    const float s1 = sinpif((float)t * (1.0f / 512.0f));

    float Y0r, Y0i, Y1r, Y1i;
    {   // k = t
        float2 A = bufB[t], Bv = bufB[512 - t];
        float Dr = A.x - Bv.x, Di = A.y + Bv.y;
        float twDr = fmaf(c1, Dr, -s1 * Di);
        float twDi = fmaf(c1, Di,  s1 * Dr);
        Y0r = 0.5f * (A.x + Bv.x) - 0.5f * twDi;
        Y0i = 0.5f * (A.y - Bv.y) + 0.5f * twDr;
    }
    {   // k = t+256
        float2 A = bufB[t + 256], Bv = bufB[256 - t];
        float Dr = A.x - Bv.x, Di = A.y + Bv.y;
        float twDr = fmaf(-s1, Dr, -c1 * Di);
        float twDi = fmaf(-s1, Di,  c1 * Dr);
        Y1r = 0.5f * (A.x + Bv.x) - 0.5f * twDi;
        Y1i = 0.5f * (A.y - Bv.y) + 0.5f * twDr;
    }

    // ---------------- Stage Ns=1 (registers) ----------------
    ((float4*)bufA)[t] = make_float4(Y0r + Y1r, Y0i + Y1i, Y0r - Y1r, Y0i - Y1i);
    __syncthreads();

    // ---------------- Stages Ns = 2..128 ----------------
    #define FFT_STAGE(NS, INVNS, SRC, DST)                                   \
    {                                                                        \
        float2 u = (SRC)[t];                                                 \
        float2 v = (SRC)[t + 256];                                           \
        int   base = t & ((NS) - 1);                                         \
        float r  = (float)base * (INVNS);                                    \
        float cw = cospif(r), sw = sinpif(r);                                \
        float vr = fmaf(cw, v.x, -sw * v.y);                                 \
        float vi = fmaf(cw, v.y,  sw * v.x);                                 \
        int dj = ((t & ~((NS) - 1)) << 1) | base;                            \
        (DST)[dj]        = make_float2(u.x + vr, u.y + vi);                  \
        (DST)[dj + (NS)] = make_float2(u.x - vr, u.y - vi);                  \
        __syncthreads();                                                     \
    }

    FFT_STAGE(2,   0.5f,        bufA, bufB)
    FFT_STAGE(4,   0.25f,       bufB, bufA)
    FFT_STAGE(8,   0.125f,      bufA, bufB)
    FFT_STAGE(16,  0.0625f,     bufB, bufA)
    FFT_STAGE(32,  0.03125f,    bufA, bufB)
    FFT_STAGE(64,  0.015625f,   bufB, bufA)
    FFT_STAGE(128, 0.0078125f,  bufA, bufB)
    #undef FFT_STAGE

    // ---------------- Stage Ns=256 -> coalesced ws store ----------------
    {
        float2 u = bufB[t];
        float2 v = bufB[t + 256];
        float r  = (float)t * (1.0f / 256.0f);
        float cw = cospif(r), sw = sinpif(r);
        float vr = fmaf(cw, v.x, -sw * v.y);
        float vi = fmaf(cw, v.y,  sw * v.x);
        const float sc = 1.0f / 512.0f;
        float2* wsq = (float2*)ws + (((q << 8) + h) << 9);  // 512 float2 per (q,h)
        // y[t]: x[2t], x[2t+1];  y[t+256]: x[2t+512], x[2t+513]
        wsq[t]       = make_float2((u.x + vr) * sc, (u.y + vi) * sc);
        wsq[t + 256] = make_float2((u.x - vr) * sc, (u.y - vi) * sc);
    }
}

// ws[q][h][s] -> out[s][q][h]; 64(h) x 64(s) tiles.
__global__ __launch_bounds__(256)
void tssm_transpose(const float* __restrict__ ws, float* __restrict__ out)
{
    __shared__ float tile[64][65];
    const int t  = threadIdx.x;
    const int hs = blockIdx.x;        // 0..3   (h tile)
    const int ss = blockIdx.y;        // 0..15  (s tile)
    const int q  = blockIdx.z;        // 0..3
    const int c  = t & 63;
    const int r0 = t >> 6;            // 0..3
    const int hbase = (q << 8) + (hs << 6);   // q*256 + hs*64

    #pragma unroll
    for (int rr = 0; rr < 64; rr += 4) {
        int hh = hbase + rr + r0;                       // row: h (q folded)
        tile[rr + r0][c] = ws[(hh << 10) + (ss << 6) + c];  // col: s
    }
    __syncthreads();
    #pragma unroll
    for (int rr = 0; rr < 64; rr += 4) {
        int s = (ss << 6) + rr + r0;
        out[(s << 10) + hbase + c] = tile[c][rr + r0];
    }
}

extern "C" void kernel_launch(void* const* d_in, const int* in_sizes, int n_in,
                              void* d_out, int out_size, void* d_ws, size_t ws_size,
                              hipStream_t stream) {
    (void)in_sizes; (void)n_in; (void)out_size; (void)ws_size;
    const float* diagonal      = (const float*)d_in[0];
    const float* lowrank       = (const float*)d_in[1];
    const float* timestep      = (const float*)d_in[2];
    const float* input_matrix  = (const float*)d_in[3];
    const float* output_matrix = (const float*)d_in[4];
    float* ws  = (float*)d_ws;   // needs Q*H*L*4 = 4 MB (ws is ~256 MB)
    float* out = (float*)d_out;

    hipLaunchKernelGGL(tssm_kernel, dim3(QQ * HH), dim3(256), 0, stream,
                       diagonal, lowrank, timestep, input_matrix, output_matrix, ws);
    hipLaunchKernelGGL(tssm_transpose, dim3(4, 16, 4), dim3(256), 0, stream,
                       ws, out);
}

// Round 5
// 23.025 us; speedup vs baseline: 5.1916x; 1.1765x over previous
//
#include <hip/hip_runtime.h>
#include <math.h>

// Problem constants: Q=4, N=64, H=256, C=1, L=1024
#define QQ 4
#define NN 64
#define HH 256

// Kernel 1: one block per (q,h), 256 threads.
//   Phase A: spectrum X[l], l = t, t+256 (resolvent sums via LDS pole table,
//            deferred-imaginary form), rank-1 correction, unit multiply.
//   Phase B: irfft(1024) as 512-pt complex inverse Stockham FFT in LDS,
//            hardware v_sin/v_cos twiddles (args in revolutions).
//   Coalesced store to ws[q][h][s].
// Kernel 2: 64x64 tile transpose ws[q][h][s] -> out[s][q][h].

__device__ __forceinline__ float vcos(float rev) { return __builtin_amdgcn_cosf(rev); }
__device__ __forceinline__ float vsin(float rev) { return __builtin_amdgcn_sinf(rev); }

__global__ __launch_bounds__(256)
void tssm_kernel(const float* __restrict__ diagonal,      // [Q][N]
                 const float* __restrict__ lowrank,       // [Q][N]
                 const float* __restrict__ timestep,      // [Q][H]
                 const float* __restrict__ input_matrix,  // [Q][N]
                 const float* __restrict__ output_matrix, // [Q][1][H][N]
                 float* __restrict__ ws)                  // [Q][H][L]
{
    __shared__ __align__(16) float2 bufA[512];
    __shared__ __align__(16) float2 bufB[513];
    __shared__ __align__(16) float4 sP4[NN];   // (a, a^2, w0=B*C, w1=B*P)
    __shared__ __align__(8)  float2 sP2[NN];   // (w2=P*C, w3=P*P)

    const int b = blockIdx.x;
    const int q = b >> 8;
    const int h = b & (HH - 1);
    const int t = threadIdx.x;

    const float tv   = __expf(timestep[q * HH + h]);
    const float invt = __builtin_amdgcn_rcpf(tv);

    // ---- pole table setup (wave 0) + X[512] ----
    if (t < NN) {
        float a  = __expf(diagonal[q * NN + t]);
        float B  = input_matrix[q * NN + t];
        float P  = lowrank[q * NN + t];
        float Cm = output_matrix[(q * HH + h) * NN + t];
        float w0 = B * Cm;
        sP4[t] = make_float4(a, a * a, w0, B * P);
        sP2[t] = make_float2(P * Cm, P * P);
        float acc = w0;
        #pragma unroll
        for (int off = 32; off >= 1; off >>= 1) acc += __shfl_xor(acc, off, 64);
        if (t == 0) bufB[512] = make_float2(0.5f * tv * acc, 0.0f);
    }
    __syncthreads();

    // ---------------- Phase A ----------------
    const float f1  = (float)t         * (1.0f / 1024.0f);
    const float f2  = (float)(t + 256) * (1.0f / 1024.0f);
    const float tn0 = sinpif(f1) * __builtin_amdgcn_rcpf(cospif(f1));
    const float tn1 = sinpif(f2) * __builtin_amdgcn_rcpf(cospif(f2));
    const float ze0 = 2.0f * tn0 * invt, ze1 = 2.0f * tn1 * invt;
    const float z20 = ze0 * ze0,         z21 = ze1 * ze1;

    // Re k_j = sum w_j * a * g ;  S_j = sum w_j * g ;  Im k_j = -zeta * S_j
    float r0_0=0,r0_1=0,r0_2=0,r0_3=0, s0_0=0,s0_1=0,s0_2=0,s0_3=0;
    float r1_0=0,r1_1=0,r1_2=0,r1_3=0, s1_0=0,s1_1=0,s1_2=0,s1_3=0;

    #pragma unroll 8
    for (int n = 0; n < NN; ++n) {
        float4 p4 = sP4[n];
        float2 p2 = sP2[n];
        {
            float g  = __builtin_amdgcn_rcpf(p4.y + z20);
            float ag = p4.x * g;
            r0_0 = fmaf(p4.z, ag, r0_0); s0_0 = fmaf(p4.z, g, s0_0);
            r0_1 = fmaf(p4.w, ag, r0_1); s0_1 = fmaf(p4.w, g, s0_1);
            r0_2 = fmaf(p2.x, ag, r0_2); s0_2 = fmaf(p2.x, g, s0_2);
            r0_3 = fmaf(p2.y, ag, r0_3); s0_3 = fmaf(p2.y, g, s0_3);
        }
        {
            float g  = __builtin_amdgcn_rcpf(p4.y + z21);
            float ag = p4.x * g;
            r1_0 = fmaf(p4.z, ag, r1_0); s1_0 = fmaf(p4.z, g, s1_0);
            r1_1 = fmaf(p4.w, ag, r1_1); s1_1 = fmaf(p4.w, g, s1_1);
            r1_2 = fmaf(p2.x, ag, r1_2); s1_2 = fmaf(p2.x, g, s1_2);
            r1_3 = fmaf(p2.y, ag, r1_3); s1_3 = fmaf(p2.y, g, s1_3);
        }
    }

    {   // bin l = t
        float i0 = -ze0 * s0_0, i1 = -ze0 * s0_1, i2 = -ze0 * s0_2, i3 = -ze0 * s0_3;
        float dr = 1.0f + r0_3, di = i3;
        float nr = r0_2 * r0_1 - i2 * i1;
        float ni = r0_2 * i1 + i2 * r0_1;
        float invm = __builtin_amdgcn_rcpf(fmaf(dr, dr, di * di));
        float qr = (nr * dr + ni * di) * invm;
        float qi = (ni * dr - nr * di) * invm;
        float Kr = r0_0 - qr, Ki = i0 - qi;
        bufB[t] = make_float2(fmaf(-tn0, Ki, Kr), fmaf(tn0, Kr, Ki));
    }
    {   // bin l = t + 256
        float i0 = -ze1 * s1_0, i1 = -ze1 * s1_1, i2 = -ze1 * s1_2, i3 = -ze1 * s1_3;
        float dr = 1.0f + r1_3, di = i3;
        float nr = r1_2 * r1_1 - i2 * i1;
        float ni = r1_2 * i1 + i2 * r1_1;
        float invm = __builtin_amdgcn_rcpf(fmaf(dr, dr, di * di));
        float qr = (nr * dr + ni * di) * invm;
        float qi = (ni * dr - nr * di) * invm;
        float Kr = r1_0 - qr, Ki = i0 - qi;
        bufB[t + 256] = make_float2(fmaf(-tn1, Ki, Kr), fmaf(tn1, Kr, Ki));
    }
    __syncthreads();

    // ---------------- Y build ----------------
    const float c1 = vcos((float)t * 0.0009765625f);   // cos(2*pi*t/1024)
    const float s1 = vsin((float)t * 0.0009765625f);

    float Y0r, Y0i, Y1r, Y1i;
    {   // k = t
        float2 A = bufB[t], Bv = bufB[512 - t];
        float Dr = A.x - Bv.x, Di = A.y + Bv.y;
        float twDr = fmaf(c1, Dr, -s1 * Di);
        float twDi = fmaf(c1, Di,  s1 * Dr);
        Y0r = 0.5f * (A.x + Bv.x) - 0.5f * twDi;
        Y0i = 0.5f * (A.y - Bv.y) + 0.5f * twDr;
    }
    {   // k = t+256
        float2 A = bufB[t + 256], Bv = bufB[256 - t];
        float Dr = A.x - Bv.x, Di = A.y + Bv.y;
        float twDr = fmaf(-s1, Dr, -c1 * Di);
        float twDi = fmaf(-s1, Di,  c1 * Dr);
        Y1r = 0.5f * (A.x + Bv.x) - 0.5f * twDi;
        Y1i = 0.5f * (A.y - Bv.y) + 0.5f * twDr;
    }

    // ---------------- Stage Ns=1 (registers) ----------------
    ((float4*)bufA)[t] = make_float4(Y0r + Y1r, Y0i + Y1i, Y0r - Y1r, Y0i - Y1i);
    __syncthreads();

    // ---------------- Stages Ns = 2..128 ----------------
    #define FFT_STAGE(NS, REVNS, SRC, DST)                                   \
    {                                                                        \
        float2 u = (SRC)[t];                                                 \
        float2 v = (SRC)[t + 256];                                           \
        int   base = t & ((NS) - 1);                                         \
        float rev = (float)base * (REVNS);                                   \
        float cw = vcos(rev), sw = vsin(rev);                                \
        float vr = fmaf(cw, v.x, -sw * v.y);                                 \
        float vi = fmaf(cw, v.y,  sw * v.x);                                 \
        int dj = ((t & ~((NS) - 1)) << 1) | base;                            \
        (DST)[dj]        = make_float2(u.x + vr, u.y + vi);                  \
        (DST)[dj + (NS)] = make_float2(u.x - vr, u.y - vi);                  \
        __syncthreads();                                                     \
    }

    FFT_STAGE(2,   0.25f,         bufA, bufB)
    FFT_STAGE(4,   0.125f,        bufB, bufA)
    FFT_STAGE(8,   0.0625f,       bufA, bufB)
    FFT_STAGE(16,  0.03125f,      bufB, bufA)
    FFT_STAGE(32,  0.015625f,     bufA, bufB)
    FFT_STAGE(64,  0.0078125f,    bufB, bufA)
    FFT_STAGE(128, 0.00390625f,   bufA, bufB)
    #undef FFT_STAGE

    // ---------------- Stage Ns=256 -> coalesced ws store ----------------
    {
        float2 u = bufB[t];
        float2 v = bufB[t + 256];
        float rev = (float)t * 0.001953125f;   // t/512 revolutions
        float cw = vcos(rev), sw = vsin(rev);
        float vr = fmaf(cw, v.x, -sw * v.y);
        float vi = fmaf(cw, v.y,  sw * v.x);
        const float sc = 1.0f / 512.0f;
        float2* wsq = (float2*)ws + (((q << 8) + h) << 9);
        wsq[t]       = make_float2((u.x + vr) * sc, (u.y + vi) * sc);
        wsq[t + 256] = make_float2((u.x - vr) * sc, (u.y - vi) * sc);
    }
}

// ws[q][h][s] -> out[s][q][h]; 64(h) x 64(s) tiles.
__global__ __launch_bounds__(256)
void tssm_transpose(const float* __restrict__ ws, float* __restrict__ out)
{
    __shared__ float tile[64][65];
    const int t  = threadIdx.x;
    const int hs = blockIdx.x;        // 0..3
    const int ss = blockIdx.y;        // 0..15
    const int q  = blockIdx.z;        // 0..3
    const int c  = t & 63;
    const int r0 = t >> 6;
    const int hbase = (q << 8) + (hs << 6);

    #pragma unroll
    for (int rr = 0; rr < 64; rr += 4) {
        int hh = hbase + rr + r0;
        tile[rr + r0][c] = ws[(hh << 10) + (ss << 6) + c];
    }
    __syncthreads();
    #pragma unroll
    for (int rr = 0; rr < 64; rr += 4) {
        int s = (ss << 6) + rr + r0;
        out[(s << 10) + hbase + c] = tile[c][rr + r0];
    }
}

extern "C" void kernel_launch(void* const* d_in, const int* in_sizes, int n_in,
                              void* d_out, int out_size, void* d_ws, size_t ws_size,
                              hipStream_t stream) {
    (void)in_sizes; (void)n_in; (void)out_size; (void)ws_size;
    const float* diagonal      = (const float*)d_in[0];
    const float* lowrank       = (const float*)d_in[1];
    const float* timestep      = (const float*)d_in[2];
    const float* input_matrix  = (const float*)d_in[3];
    const float* output_matrix = (const float*)d_in[4];
    float* ws  = (float*)d_ws;
    float* out = (float*)d_out;

    hipLaunchKernelGGL(tssm_kernel, dim3(QQ * HH), dim3(256), 0, stream,
                       diagonal, lowrank, timestep, input_matrix, output_matrix, ws);
    hipLaunchKernelGGL(tssm_transpose, dim3(4, 16, 4), dim3(256), 0, stream,
                       ws, out);
}